// Round 1
// baseline (798.618 us; speedup 1.0000x reference)
//
#include <hip/hip_runtime.h>

#define NN 100000
#define NE 1600000
#define DF 128
#define NC 47

// ---------------- CSR build ----------------

__global__ void k_count(const int* __restrict__ dst, int* __restrict__ cnt) {
    int i = blockIdx.x * blockDim.x + threadIdx.x;
    if (i < NE) atomicAdd(&cnt[dst[i]], 1);
}

// block-level exclusive scan over 1024-chunks; writes block totals
__global__ void k_scan1(int* __restrict__ buf, int* __restrict__ part, int n) {
    __shared__ int s[1024];
    int t = threadIdx.x;
    int i = blockIdx.x * 1024 + t;
    int c = (i < n) ? buf[i] : 0;
    s[t] = c;
    __syncthreads();
    for (int off = 1; off < 1024; off <<= 1) {
        int v = (t >= off) ? s[t - off] : 0;
        __syncthreads();
        s[t] += v;
        __syncthreads();
    }
    if (i < n) buf[i] = s[t] - c;              // exclusive within block
    if (t == 1023) part[blockIdx.x] = s[t];    // block total
}

__global__ void k_scan2(int* part, int np) {
    if (threadIdx.x == 0 && blockIdx.x == 0) {
        int run = 0;
        for (int i = 0; i < np; ++i) { int v = part[i]; part[i] = run; run += v; }
    }
}

__global__ void k_scan3(int* __restrict__ buf, const int* __restrict__ part, int n) {
    int i = blockIdx.x * blockDim.x + threadIdx.x;
    if (i < n) buf[i] += part[i >> 10];
}

__global__ void k_initcur(const int* __restrict__ rp, int* __restrict__ cur) {
    int i = blockIdx.x * blockDim.x + threadIdx.x;
    if (i < NN) cur[i] = rp[i];
}

__global__ void k_fill(const int* __restrict__ src, const int* __restrict__ dst,
                       int* __restrict__ cur, int* __restrict__ col) {
    int i = blockIdx.x * blockDim.x + threadIdx.x;
    if (i < NE) {
        int d = dst[i];
        int p = atomicAdd(&cur[d], 1);
        col[p] = src[i];
    }
}

// ---------------- mean-aggregate gather: one wave per dst node ----------------

__global__ __launch_bounds__(256) void k_gather(
        const float* __restrict__ h, const int* __restrict__ rp,
        const int* __restrict__ col, float* __restrict__ hn) {
    int node = blockIdx.x * 4 + (threadIdx.x >> 6);
    int lane = threadIdx.x & 63;
    if (node >= NN) return;
    int beg = rp[node], end = rp[node + 1];
    const float2* hp = (const float2*)h;
    float ax0 = 0.f, ay0 = 0.f, ax1 = 0.f, ay1 = 0.f;
    int e = beg;
    for (; e + 2 <= end; e += 2) {
        int s0 = col[e], s1 = col[e + 1];
        float2 v0 = hp[(size_t)s0 * 64 + lane];
        float2 v1 = hp[(size_t)s1 * 64 + lane];
        ax0 += v0.x; ay0 += v0.y; ax1 += v1.x; ay1 += v1.y;
    }
    if (e < end) {
        int s = col[e];
        float2 v = hp[(size_t)s * 64 + lane];
        ax0 += v.x; ay0 += v.y;
    }
    float d = (float)(end - beg);
    float inv = (d > 0.f) ? 1.0f / d : 0.0f;
    float2 o; o.x = (ax0 + ax1) * inv; o.y = (ay0 + ay1) * inv;
    ((float2*)hn)[(size_t)node * 64 + lane] = o;
}

// ---------------- fused GEMM: out = h@Ws + hn@Wn + b (+relu), N=128 ----------------

template<bool RELU>
__global__ __launch_bounds__(256) void k_gemm128(
        const float* __restrict__ h, const float* __restrict__ hn,
        const float* __restrict__ Ws, const float* __restrict__ Wn,
        const float* __restrict__ bias, float* __restrict__ out) {
    __shared__ float As[16][68];   // k-major, padded
    __shared__ float Bs[16][128];
    int t = threadIdx.x;
    int row0 = blockIdx.x * 64;
    int tx = t & 31;        // col quad: cols tx*4 .. tx*4+3
    int ty = t >> 5;        // row group: rows ty*8 .. ty*8+7
    float acc[8][4];
#pragma unroll
    for (int r = 0; r < 8; ++r)
#pragma unroll
        for (int j = 0; j < 4; ++j) acc[r][j] = 0.f;

    for (int phase = 0; phase < 2; ++phase) {
        const float* A = phase ? hn : h;
        const float* W = phase ? Wn : Ws;
        for (int kc = 0; kc < 128; kc += 16) {
            // A tile: 64 rows x 16 k, transposed into LDS
            {
                int r = t >> 2, q = t & 3;
                int row = row0 + r; if (row >= NN) row = NN - 1;
                const float4 av = *(const float4*)&A[(size_t)row * 128 + kc + q * 4];
                As[q * 4 + 0][r] = av.x;
                As[q * 4 + 1][r] = av.y;
                As[q * 4 + 2][r] = av.z;
                As[q * 4 + 3][r] = av.w;
            }
            // B tile: 16 k x 128 cols
            {
                int kk = t >> 5, c4 = t & 31;
                *(float4*)&Bs[kk][c4 * 4]     = *(const float4*)&W[(size_t)(kc + kk) * 128 + c4 * 4];
                *(float4*)&Bs[kk + 8][c4 * 4] = *(const float4*)&W[(size_t)(kc + kk + 8) * 128 + c4 * 4];
            }
            __syncthreads();
#pragma unroll
            for (int k = 0; k < 16; ++k) {
                float4 a0 = *(const float4*)&As[k][ty * 8];
                float4 a1 = *(const float4*)&As[k][ty * 8 + 4];
                float4 bv = *(const float4*)&Bs[k][tx * 4];
                float a[8] = {a0.x, a0.y, a0.z, a0.w, a1.x, a1.y, a1.z, a1.w};
#pragma unroll
                for (int r = 0; r < 8; ++r) {
                    acc[r][0] += a[r] * bv.x;
                    acc[r][1] += a[r] * bv.y;
                    acc[r][2] += a[r] * bv.z;
                    acc[r][3] += a[r] * bv.w;
                }
            }
            __syncthreads();
        }
    }
    float4 bv = *(const float4*)&bias[tx * 4];
    float bb[4] = {bv.x, bv.y, bv.z, bv.w};
#pragma unroll
    for (int r = 0; r < 8; ++r) {
        int row = row0 + ty * 8 + r;
        if (row < NN) {
            float4 o;
            o.x = acc[r][0] + bb[0];
            o.y = acc[r][1] + bb[1];
            o.z = acc[r][2] + bb[2];
            o.w = acc[r][3] + bb[3];
            if (RELU) {
                o.x = fmaxf(o.x, 0.f); o.y = fmaxf(o.y, 0.f);
                o.z = fmaxf(o.z, 0.f); o.w = fmaxf(o.w, 0.f);
            }
            *(float4*)&out[(size_t)row * 128 + tx * 4] = o;
        }
    }
}

// ---------------- fused GEMM layer 2: N=47 (padded 48) ----------------

__global__ __launch_bounds__(192) void k_gemm47(
        const float* __restrict__ h, const float* __restrict__ hn,
        const float* __restrict__ Ws, const float* __restrict__ Wn,
        const float* __restrict__ bias, float* __restrict__ out) {
    __shared__ float As[16][68];
    __shared__ float Bs[16][48];
    int t = threadIdx.x;
    int row0 = blockIdx.x * 64;
    int tx = t % 12;        // cols tx*4 .. tx*4+3 (48 padded)
    int ty = t / 12;        // rows ty*4 .. ty*4+3  (ty 0..15)
    float acc[4][4];
#pragma unroll
    for (int r = 0; r < 4; ++r)
#pragma unroll
        for (int j = 0; j < 4; ++j) acc[r][j] = 0.f;

    for (int phase = 0; phase < 2; ++phase) {
        const float* A = phase ? hn : h;
        const float* W = phase ? Wn : Ws;
        for (int kc = 0; kc < 128; kc += 16) {
            // A tile: 256 float4s, strided over 192 threads
            for (int i = t; i < 256; i += 192) {
                int r = i >> 2, q = i & 3;
                int row = row0 + r; if (row >= NN) row = NN - 1;
                const float4 av = *(const float4*)&A[(size_t)row * 128 + kc + q * 4];
                As[q * 4 + 0][r] = av.x;
                As[q * 4 + 1][r] = av.y;
                As[q * 4 + 2][r] = av.z;
                As[q * 4 + 3][r] = av.w;
            }
            // B tile: 16 x 48 (col >= 47 zero-padded)
            for (int i = t; i < 768; i += 192) {
                int kk = i / 48, c = i % 48;
                Bs[kk][c] = (c < 47) ? W[(size_t)(kc + kk) * 47 + c] : 0.0f;
            }
            __syncthreads();
#pragma unroll
            for (int k = 0; k < 16; ++k) {
                float4 a = *(const float4*)&As[k][ty * 4];
                float4 b = *(const float4*)&Bs[k][tx * 4];
                float av[4] = {a.x, a.y, a.z, a.w};
#pragma unroll
                for (int r = 0; r < 4; ++r) {
                    acc[r][0] += av[r] * b.x;
                    acc[r][1] += av[r] * b.y;
                    acc[r][2] += av[r] * b.z;
                    acc[r][3] += av[r] * b.w;
                }
            }
            __syncthreads();
        }
    }
#pragma unroll
    for (int r = 0; r < 4; ++r) {
        int row = row0 + ty * 4 + r;
        if (row < NN) {
#pragma unroll
            for (int j = 0; j < 4; ++j) {
                int c = tx * 4 + j;
                if (c < 47) out[(size_t)row * 47 + c] = acc[r][j] + bias[c];
            }
        }
    }
}

// ---------------- launcher ----------------

static inline size_t align_up(size_t x, size_t a) { return (x + a - 1) / a * a; }

extern "C" void kernel_launch(void* const* d_in, const int* in_sizes, int n_in,
                              void* d_out, int out_size, void* d_ws, size_t ws_size,
                              hipStream_t stream) {
    const float* x   = (const float*)d_in[0];
    const int* src   = (const int*)d_in[1];
    const int* dst   = (const int*)d_in[2];
    const float* Ws0 = (const float*)d_in[3];
    const float* Wn0 = (const float*)d_in[4];
    const float* b0  = (const float*)d_in[5];
    const float* Ws1 = (const float*)d_in[6];
    const float* Wn1 = (const float*)d_in[7];
    const float* b1  = (const float*)d_in[8];
    const float* Ws2 = (const float*)d_in[9];
    const float* Wn2 = (const float*)d_in[10];
    const float* b2  = (const float*)d_in[11];
    float* out = (float*)d_out;

    char* ws = (char*)d_ws;
    size_t off = 0;
    int* row_ptr = (int*)(ws + off); off = align_up(off + (NN + 1) * sizeof(int), 256);
    int* cursor  = (int*)(ws + off); off = align_up(off + NN * sizeof(int), 256);
    int* part    = (int*)(ws + off); off = align_up(off + 256 * sizeof(int), 256);
    int* col     = (int*)(ws + off); off = align_up(off + NE * sizeof(int), 256);
    float* HN    = (float*)(ws + off); off = align_up(off + (size_t)NN * DF * sizeof(float), 256);
    float* H     = (float*)(ws + off); off = align_up(off + (size_t)NN * DF * sizeof(float), 256);

    // --- CSR build ---
    hipMemsetAsync(row_ptr, 0, (NN + 1) * sizeof(int), stream);
    k_count<<<(NE + 255) / 256, 256, 0, stream>>>(dst, row_ptr);
    int nscan = NN + 1;
    int nb1 = (nscan + 1023) / 1024;   // 98
    k_scan1<<<nb1, 1024, 0, stream>>>(row_ptr, part, nscan);
    k_scan2<<<1, 1, 0, stream>>>(part, nb1);
    k_scan3<<<(nscan + 255) / 256, 256, 0, stream>>>(row_ptr, part, nscan);
    k_initcur<<<(NN + 255) / 256, 256, 0, stream>>>(row_ptr, cursor);
    k_fill<<<(NE + 255) / 256, 256, 0, stream>>>(src, dst, cursor, col);

    int ggrid = (NN + 3) / 4;          // 4 waves (nodes) per 256-thread block
    int mgrid = (NN + 63) / 64;        // 64 rows per block

    // --- layer 0 ---
    k_gather<<<ggrid, 256, 0, stream>>>(x, row_ptr, col, HN);
    k_gemm128<true><<<mgrid, 256, 0, stream>>>(x, HN, Ws0, Wn0, b0, H);
    // --- layer 1 (gemm in-place over H) ---
    k_gather<<<ggrid, 256, 0, stream>>>(H, row_ptr, col, HN);
    k_gemm128<true><<<mgrid, 256, 0, stream>>>(H, HN, Ws1, Wn1, b1, H);
    // --- layer 2 ---
    k_gather<<<ggrid, 256, 0, stream>>>(H, row_ptr, col, HN);
    k_gemm47<<<mgrid, 192, 0, stream>>>(H, HN, Ws2, Wn2, b2, out);
}